// Round 6
// baseline (257.383 us; speedup 1.0000x reference)
//
#include <hip/hip_runtime.h>
#include <hip/hip_bf16.h>

#define Bn 8
#define Nn 4096
#define Cn 1024
#define Dn 512
#define Mn 64

typedef __hip_bfloat16 bf16;
typedef __attribute__((ext_vector_type(8))) short short8;
typedef __attribute__((ext_vector_type(4))) short short4x;
typedef __attribute__((ext_vector_type(4))) float f32x4;

#define MFMA16(a, b, c) __builtin_amdgcn_mfma_f32_16x16x32_bf16((a), (b), (c), 0, 0, 0)

__device__ inline short bfbits(float f) {
  union { bf16 b; short s; } u;
  u.b = __float2bfloat16(f);
  return u.s;
}

__device__ inline short8 pack8(const float4& a, const float4& b) {
  short8 s;
  s[0] = bfbits(a.x); s[1] = bfbits(a.y); s[2] = bfbits(a.z); s[3] = bfbits(a.w);
  s[4] = bfbits(b.x); s[5] = bfbits(b.y); s[6] = bfbits(b.z); s[7] = bfbits(b.w);
  return s;
}

// ---------------------------------------------------------------------------
// K0: V[m][c] = sum_d av[m][d]*W[d][c]  (bf16 hi+lo);  c0[m] = av[m,:].bias
// ---------------------------------------------------------------------------
__global__ __launch_bounds__(256) void prep_kernel(
    const float* __restrict__ W, const float* __restrict__ bias,
    const float* __restrict__ av, bf16* __restrict__ Vhi,
    bf16* __restrict__ Vlo, float* __restrict__ c0) {
  const int m = blockIdx.x;
  const int t = threadIdx.x;
  const int cl = t & 63, dg = t >> 6;
  const int c = blockIdx.y * 64 + cl;
  const float* wp = W + (size_t)(dg * 128) * Cn + c;
  const float* ap = av + m * Dn + dg * 128;
  float a0 = 0.f, a1 = 0.f, a2 = 0.f, a3 = 0.f;
#pragma unroll 8
  for (int i = 0; i < 128; i += 4) {
    a0 = fmaf(ap[i + 0], wp[(size_t)(i + 0) * Cn], a0);
    a1 = fmaf(ap[i + 1], wp[(size_t)(i + 1) * Cn], a1);
    a2 = fmaf(ap[i + 2], wp[(size_t)(i + 2) * Cn], a2);
    a3 = fmaf(ap[i + 3], wp[(size_t)(i + 3) * Cn], a3);
  }
  __shared__ float red[256];
  red[t] = (a0 + a1) + (a2 + a3);
  __syncthreads();
  const float v = red[cl] + red[cl + 64] + red[cl + 128] + red[cl + 192];
  if (dg == 0) {
    const bf16 hi = __float2bfloat16(v);
    Vhi[m * Cn + c] = hi;
    Vlo[m * Cn + c] = __float2bfloat16(v - __bfloat162float(hi));
  }
  if (blockIdx.y == 0) {
    __syncthreads();
    red[t] = av[m * Dn + t] * bias[t] + av[m * Dn + t + 256] * bias[t + 256];
    __syncthreads();
    if (t < 64) {
      float s = red[t] + red[t + 64] + red[t + 128] + red[t + 192];
#pragma unroll
      for (int off = 32; off > 0; off >>= 1) s += __shfl_down(s, off);
      if (t == 0) c0[m] = s;
    }
  }
}

// ---------------------------------------------------------------------------
// K1: logits[b][m][n] = x[b][n][:].V[m][:] + c0[m]
// 512-thread blocks (8 waves): wave = 16n x 32m.  K-chunk 64, double-buffered
// V hi/lo in LDS (one 512-thread staging round), x direct global->reg,
// 1 barrier/chunk, 1-chunk-ahead prefetch.  16 waves/CU.
// grid (Nn/64, Bn) = 512; LDS 36.9 KB -> 2 blocks/CU.
// ---------------------------------------------------------------------------
__global__ __launch_bounds__(512) void logits_kernel(
    const float* __restrict__ x, const bf16* __restrict__ Vhi,
    const bf16* __restrict__ Vlo, const float* __restrict__ c0,
    float* __restrict__ logits) {
  const int n0 = blockIdx.x * 64;
  const int b = blockIdx.y;
  const int t = threadIdx.x;
  __shared__ short Vs[2][2][64][72];  // [buf][hi/lo][m][k]
  const int w = t >> 6, lane = t & 63, lr = lane & 15, q = lane >> 4;
  const int nq = w & 3;          // n-group (16 rows)
  const int mtb = (w >> 2) * 2;  // m-frag base (2 frags of 16)

  // V staging: one round: row = t>>3 (0..63), seg = (t&7)*8 shorts
  const int vr = t >> 3, vc = (t & 7) * 8;
  const bf16* hsrc = Vhi + vr * Cn + vc;
  const bf16* lsrc = Vlo + vr * Cn + vc;
  const float* xrow = x + (size_t)(b * Nn + n0 + nq * 16 + lr) * Cn + q * 8;

  f32x4 acc[2];
  acc[0] = (f32x4){0.f, 0.f, 0.f, 0.f};
  acc[1] = (f32x4){0.f, 0.f, 0.f, 0.f};

  short8 vh, vl;
  float4 xs0, xs1, xs2, xs3;

  // prologue: V(0)->LDS[0]; V(1)->regs; x(0)->regs
  vh = *(const short8*)(hsrc);
  vl = *(const short8*)(lsrc);
  xs0 = *(const float4*)(xrow);
  xs1 = *(const float4*)(xrow + 4);
  xs2 = *(const float4*)(xrow + 32);
  xs3 = *(const float4*)(xrow + 36);
  *(short8*)&Vs[0][0][vr][vc] = vh;
  *(short8*)&Vs[0][1][vr][vc] = vl;
  vh = *(const short8*)(hsrc + 64);
  vl = *(const short8*)(lsrc + 64);
  __syncthreads();

#pragma unroll
  for (int kc = 0; kc < 16; ++kc) {
    const int buf = kc & 1;
    const short8 a0 = pack8(xs0, xs1);
    const short8 a1 = pack8(xs2, xs3);
    if (kc < 15) {
      const int k1 = (kc + 1) * 64;
      xs0 = *(const float4*)(xrow + k1);
      xs1 = *(const float4*)(xrow + k1 + 4);
      xs2 = *(const float4*)(xrow + k1 + 32);
      xs3 = *(const float4*)(xrow + k1 + 36);
    }
    if (kc < 15) {
      *(short8*)&Vs[buf ^ 1][0][vr][vc] = vh;
      *(short8*)&Vs[buf ^ 1][1][vr][vc] = vl;
    }
    if (kc < 14) {
      const int k2 = (kc + 2) * 64;
      vh = *(const short8*)(hsrc + k2);
      vl = *(const short8*)(lsrc + k2);
    }
#pragma unroll
    for (int kk2 = 0; kk2 < 2; ++kk2) {
      const short8 a = kk2 ? a1 : a0;
      const int ko = kk2 * 32 + q * 8;
#pragma unroll
      for (int i = 0; i < 2; ++i) {
        const int mt = mtb + i;
        acc[i] = MFMA16(a, *(const short8*)&Vs[buf][0][mt * 16 + lr][ko], acc[i]);
        acc[i] = MFMA16(a, *(const short8*)&Vs[buf][1][mt * 16 + lr][ko], acc[i]);
      }
    }
    __syncthreads();
  }

  // epilogue: accs -> LDS transpose -> coalesced stores
  float (*LT)[68] = reinterpret_cast<float(*)[68]>(&Vs[0][0][0][0]);
#pragma unroll
  for (int i = 0; i < 2; ++i) {
    const int m = (mtb + i) * 16 + lr;
    f32x4 o = acc[i];
    const float bb = c0[m];
    o[0] += bb; o[1] += bb; o[2] += bb; o[3] += bb;
    *(f32x4*)&LT[m][nq * 16 + q * 4] = o;
  }
  __syncthreads();
  {
    const int mr = t >> 3, seg = (t & 7) * 8;
    float* dst = logits + (size_t)(b * Mn + mr) * Nn + n0 + seg;
    *(float4*)(dst) = *(const float4*)&LT[mr][seg];
    *(float4*)(dst + 4) = *(const float4*)&LT[mr][seg + 4];
  }
}

// ---------------------------------------------------------------------------
// K2: softmax over N per (b,m) row; bf16 weights out. grid Bn*Mn, block 256
// ---------------------------------------------------------------------------
__global__ __launch_bounds__(256) void softmax_kernel(
    const float* __restrict__ logits, bf16* __restrict__ wgt) {
  const int row = blockIdx.x;
  const int t = threadIdx.x;
  const float* L = logits + (size_t)row * Nn;
  float v[16];
  float mx = -3.4e38f;
#pragma unroll
  for (int i = 0; i < 16; ++i) {
    v[i] = L[t + 256 * i];
    mx = fmaxf(mx, v[i]);
  }
#pragma unroll
  for (int off = 32; off > 0; off >>= 1) mx = fmaxf(mx, __shfl_down(mx, off));
  __shared__ float sred[4];
  if ((t & 63) == 0) sred[t >> 6] = mx;
  __syncthreads();
  mx = fmaxf(fmaxf(sred[0], sred[1]), fmaxf(sred[2], sred[3]));
  float sum = 0.f;
#pragma unroll
  for (int i = 0; i < 16; ++i) {
    v[i] = __expf(v[i] - mx);
    sum += v[i];
  }
#pragma unroll
  for (int off = 32; off > 0; off >>= 1) sum += __shfl_down(sum, off);
  __syncthreads();
  if ((t & 63) == 0) sred[t >> 6] = sum;
  __syncthreads();
  const float inv = 1.f / (sred[0] + sred[1] + sred[2] + sred[3]);
#pragma unroll
  for (int i = 0; i < 16; ++i)
    wgt[(size_t)row * Nn + t + 256 * i] = __float2bfloat16(v[i] * inv);
}

// ---------------------------------------------------------------------------
// K3: part[ks][b][m][c] = sum_{k in eighth ks} wgt[b][m][k]*x[b][k][c]
// 512-thread blocks (8 waves): tile 64m x 128c, wave = 32m x 32c.
// K-chunk 64 (8 chunks), double-buffered swizzled x-transpose in LDS,
// wgt A-frags direct global->reg, 1 barrier/chunk, prefetch 1 chunk.
// grid (Cn/128, Bn, 8) = 512; LDS 36.9 KB -> 2 blocks/CU, 16 waves/CU.
// ---------------------------------------------------------------------------
__global__ __launch_bounds__(512) void pool_kernel(
    const float* __restrict__ x, const bf16* __restrict__ wgt,
    float* __restrict__ part) {
  const int cbase = blockIdx.x * 128;
  const int b = blockIdx.y;
  const int ks = blockIdx.z;
  const int t = threadIdx.x;
  __shared__ short XT[2][128][72];  // [buf][c][k^swz]
  const int w = t >> 6, lane = t & 63, lr = lane & 15, q = lane >> 4;
  const int mh = (w & 1) * 32, ch = (w >> 1) * 32;  // m-half, c-quarter
  f32x4 acc[2][2];
#pragma unroll
  for (int i = 0; i < 2; ++i)
#pragma unroll
    for (int j = 0; j < 2; ++j) acc[i][j] = (f32x4){0.f, 0.f, 0.f, 0.f};

  const int h = t & 31, g = t >> 5;  // c-seg 4h (0..127), k-rows 4g..4g+3
  const int swz = 8 * (h & 7);
  const int swzr0 = 8 * (((ch + lr) >> 2) & 7);
  const int swzr1 = 8 * (((ch + 16 + lr) >> 2) & 7);
  const int kbase = ks * (Nn / 8);
  const float* xsrc = x + (size_t)b * Nn * Cn + (size_t)(kbase + 4 * g) * Cn + cbase + 4 * h;
  const bf16* wr0 = wgt + (size_t)(b * Mn + mh + lr) * Nn + kbase + q * 8;
  const bf16* wr1 = wr0 + (size_t)16 * Nn;

  float4 p0, p1, p2, p3;
  short8 aw0, aw1, aw2, aw3;

  // prologue: x(0)->regs->LDS[0]; x(1)->regs; wgt(0)->regs
  p0 = *(const float4*)(xsrc);
  p1 = *(const float4*)(xsrc + Cn);
  p2 = *(const float4*)(xsrc + 2 * Cn);
  p3 = *(const float4*)(xsrc + 3 * Cn);
  aw0 = *(const short8*)(wr0);
  aw1 = *(const short8*)(wr0 + 32);
  aw2 = *(const short8*)(wr1);
  aw3 = *(const short8*)(wr1 + 32);
  {
    const int kof = (4 * g) ^ swz;
    short4x v0, v1, v2, v3;
    v0[0] = bfbits(p0.x); v0[1] = bfbits(p1.x); v0[2] = bfbits(p2.x); v0[3] = bfbits(p3.x);
    v1[0] = bfbits(p0.y); v1[1] = bfbits(p1.y); v1[2] = bfbits(p2.y); v1[3] = bfbits(p3.y);
    v2[0] = bfbits(p0.z); v2[1] = bfbits(p1.z); v2[2] = bfbits(p2.z); v2[3] = bfbits(p3.z);
    v3[0] = bfbits(p0.w); v3[1] = bfbits(p1.w); v3[2] = bfbits(p2.w); v3[3] = bfbits(p3.w);
    *(short4x*)&XT[0][4 * h + 0][kof] = v0;
    *(short4x*)&XT[0][4 * h + 1][kof] = v1;
    *(short4x*)&XT[0][4 * h + 2][kof] = v2;
    *(short4x*)&XT[0][4 * h + 3][kof] = v3;
  }
  p0 = *(const float4*)(xsrc + (size_t)64 * Cn);
  p1 = *(const float4*)(xsrc + (size_t)65 * Cn);
  p2 = *(const float4*)(xsrc + (size_t)66 * Cn);
  p3 = *(const float4*)(xsrc + (size_t)67 * Cn);
  __syncthreads();

#pragma unroll
  for (int kc = 0; kc < 8; ++kc) {
    const int buf = kc & 1;
    const short8 a00 = aw0, a01 = aw1, a10 = aw2, a11 = aw3;
    if (kc < 7) {
      const int k1 = (kc + 1) * 64;
      aw0 = *(const short8*)(wr0 + k1);
      aw1 = *(const short8*)(wr0 + k1 + 32);
      aw2 = *(const short8*)(wr1 + k1);
      aw3 = *(const short8*)(wr1 + k1 + 32);
    }
    if (kc < 7) {
      const int kof = (4 * g) ^ swz;
      short4x v0, v1, v2, v3;
      v0[0] = bfbits(p0.x); v0[1] = bfbits(p1.x); v0[2] = bfbits(p2.x); v0[3] = bfbits(p3.x);
      v1[0] = bfbits(p0.y); v1[1] = bfbits(p1.y); v1[2] = bfbits(p2.y); v1[3] = bfbits(p3.y);
      v2[0] = bfbits(p0.z); v2[1] = bfbits(p1.z); v2[2] = bfbits(p2.z); v2[3] = bfbits(p3.z);
      v3[0] = bfbits(p0.w); v3[1] = bfbits(p1.w); v3[2] = bfbits(p2.w); v3[3] = bfbits(p3.w);
      *(short4x*)&XT[buf ^ 1][4 * h + 0][kof] = v0;
      *(short4x*)&XT[buf ^ 1][4 * h + 1][kof] = v1;
      *(short4x*)&XT[buf ^ 1][4 * h + 2][kof] = v2;
      *(short4x*)&XT[buf ^ 1][4 * h + 3][kof] = v3;
    }
    if (kc < 6) {
      const size_t roff = (size_t)(kc + 2) * 64 * Cn;
      p0 = *(const float4*)(xsrc + roff);
      p1 = *(const float4*)(xsrc + roff + Cn);
      p2 = *(const float4*)(xsrc + roff + 2 * Cn);
      p3 = *(const float4*)(xsrc + roff + 3 * Cn);
    }
#pragma unroll
    for (int kk2 = 0; kk2 < 2; ++kk2) {
      const int ko = kk2 * 32 + q * 8;
      const short8 b0 = *(const short8*)&XT[buf][ch + lr][ko ^ swzr0];
      const short8 b1 = *(const short8*)&XT[buf][ch + 16 + lr][ko ^ swzr1];
      const short8 aa = kk2 ? a01 : a00;
      const short8 ab = kk2 ? a11 : a10;
      acc[0][0] = MFMA16(aa, b0, acc[0][0]);
      acc[0][1] = MFMA16(aa, b1, acc[0][1]);
      acc[1][0] = MFMA16(ab, b0, acc[1][0]);
      acc[1][1] = MFMA16(ab, b1, acc[1][1]);
    }
    __syncthreads();
  }

  float* pout = part + ((size_t)ks * Bn + b) * Mn * Cn;
#pragma unroll
  for (int mi = 0; mi < 2; ++mi)
#pragma unroll
    for (int ci = 0; ci < 2; ++ci) {
      const int m = mh + mi * 16 + q * 4;
      const int c = cbase + ch + ci * 16 + lr;
#pragma unroll
      for (int reg = 0; reg < 4; ++reg)
        pout[(size_t)(m + reg) * Cn + c] = acc[mi][ci][reg];
    }
}

// ---------------------------------------------------------------------------
// K4: out = sum of 8 partials (float4).  grid 512, block 256
// ---------------------------------------------------------------------------
__global__ __launch_bounds__(256) void reduce_kernel(
    const float* __restrict__ part, float* __restrict__ out) {
  const int i = blockIdx.x * 256 + threadIdx.x;
  const float4* p = (const float4*)part;
  const int S4 = (Bn * Mn * Cn) / 4;
  float4 o = p[i];
#pragma unroll
  for (int j = 1; j < 8; ++j) {
    const float4 v = p[i + j * S4];
    o.x += v.x; o.y += v.y; o.z += v.z; o.w += v.w;
  }
  ((float4*)out)[i] = o;
}

extern "C" void kernel_launch(void* const* d_in, const int* in_sizes, int n_in,
                              void* d_out, int out_size, void* d_ws, size_t ws_size,
                              hipStream_t stream) {
  const float* x = (const float*)d_in[0];
  const float* W = (const float*)d_in[1];
  const float* bias = (const float*)d_in[2];
  const float* av = (const float*)d_in[3];
  float* out = (float*)d_out;
  char* ws = (char*)d_ws;

  bf16* Vhi = (bf16*)(ws + 0);            // 131072 B
  bf16* Vlo = (bf16*)(ws + 131072);       // 131072 B
  float* c0 = (float*)(ws + 262144);      // 1024 B
  float* logits = (float*)(ws + 263168);  // 8388608 B
  bf16* wgt = (bf16*)(ws + 8651776);      // 4194304 B
  float* part = (float*)(ws + 12846080);  // 8 x 2097152 B  (total ~29.6 MB)

  prep_kernel<<<dim3(Mn, Cn / 64), 256, 0, stream>>>(W, bias, av, Vhi, Vlo, c0);
  logits_kernel<<<dim3(Nn / 64, Bn), 512, 0, stream>>>(x, Vhi, Vlo, c0, logits);
  softmax_kernel<<<Bn * Mn, 256, 0, stream>>>(logits, wgt);
  pool_kernel<<<dim3(Cn / 128, Bn, 8), 512, 0, stream>>>(x, wgt, part);
  reduce_kernel<<<(Bn * Mn * Cn) / 1024, 256, 0, stream>>>(part, out);
}

// Round 7
// 244.514 us; speedup vs baseline: 1.0526x; 1.0526x over previous
//
#include <hip/hip_runtime.h>
#include <hip/hip_bf16.h>

#define Bn 8
#define Nn 4096
#define Cn 1024
#define Dn 512
#define Mn 64

typedef __hip_bfloat16 bf16;
typedef __attribute__((ext_vector_type(8))) short short8;
typedef __attribute__((ext_vector_type(4))) short short4x;
typedef __attribute__((ext_vector_type(4))) float f32x4;

#define MFMA16(a, b, c) __builtin_amdgcn_mfma_f32_16x16x32_bf16((a), (b), (c), 0, 0, 0)

__device__ inline short bfbits(float f) {
  union { bf16 b; short s; } u;
  u.b = __float2bfloat16(f);
  return u.s;
}

// ---------------------------------------------------------------------------
// K0: V[m][c] = sum_d av[m][d]*W[d][c]  (bf16 hi+lo);  c0[m] = av[m,:].bias
// grid (Mn, Cn/64) = 1024 blocks, block 256 = 64c x 4 d-groups (ILP + LDS red)
// ---------------------------------------------------------------------------
__global__ __launch_bounds__(256) void prep_kernel(
    const float* __restrict__ W, const float* __restrict__ bias,
    const float* __restrict__ av, bf16* __restrict__ Vhi,
    bf16* __restrict__ Vlo, float* __restrict__ c0) {
  const int m = blockIdx.x;
  const int t = threadIdx.x;
  const int cl = t & 63, dg = t >> 6;
  const int c = blockIdx.y * 64 + cl;
  const float* wp = W + (size_t)(dg * 128) * Cn + c;
  const float* ap = av + m * Dn + dg * 128;
  float a0 = 0.f, a1 = 0.f, a2 = 0.f, a3 = 0.f;
#pragma unroll 8
  for (int i = 0; i < 128; i += 4) {
    a0 = fmaf(ap[i + 0], wp[(size_t)(i + 0) * Cn], a0);
    a1 = fmaf(ap[i + 1], wp[(size_t)(i + 1) * Cn], a1);
    a2 = fmaf(ap[i + 2], wp[(size_t)(i + 2) * Cn], a2);
    a3 = fmaf(ap[i + 3], wp[(size_t)(i + 3) * Cn], a3);
  }
  __shared__ float red[256];
  red[t] = (a0 + a1) + (a2 + a3);
  __syncthreads();
  const float v = red[cl] + red[cl + 64] + red[cl + 128] + red[cl + 192];
  if (dg == 0) {
    const bf16 hi = __float2bfloat16(v);
    Vhi[m * Cn + c] = hi;
    Vlo[m * Cn + c] = __float2bfloat16(v - __bfloat162float(hi));
  }
  if (blockIdx.y == 0) {  // block-uniform
    __syncthreads();
    red[t] = av[m * Dn + t] * bias[t] + av[m * Dn + t + 256] * bias[t + 256];
    __syncthreads();
    if (t < 64) {
      float s = red[t] + red[t + 64] + red[t + 128] + red[t + 192];
#pragma unroll
      for (int off = 32; off > 0; off >>= 1) s += __shfl_down(s, off);
      if (t == 0) c0[m] = s;
    }
  }
}

// ---------------------------------------------------------------------------
// K1: logits[b][m][n] = x[b][n][:].V[m][:] + c0[m]
// Tile 64n x 64m, K-chunks of 128.  x (fp32->bf16), Vhi, Vlo all staged in
// LDS with fully-coalesced loads (16 adjacent lanes -> 512B contiguous) and
// 1-chunk-ahead register prefetch.  Stride 136 shorts: 2-way banks (free).
// grid (Nn/64, Bn) = 512, block 256 (4 waves); LDS 52KB -> 3 blocks/CU.
// ---------------------------------------------------------------------------
__global__ __launch_bounds__(256) void logits_kernel(
    const float* __restrict__ x, const bf16* __restrict__ Vhi,
    const bf16* __restrict__ Vlo, const float* __restrict__ c0,
    float* __restrict__ logits) {
  const int n0 = blockIdx.x * 64;
  const int b = blockIdx.y;
  const int t = threadIdx.x;
  __shared__ short Xs[64][136];
  __shared__ short VsH[64][136];
  __shared__ short VsL[64][136];
  const int w = t >> 6, lane = t & 63, lr = lane & 15, q = lane >> 4;
  const ptrdiff_t dlo = Vlo - Vhi;

  // staging unit u = t + 256j: row = u>>4, col-16B-unit = u&15
  int ur[4], uc[4];
  const float* xsrc[4];
  const bf16* hsrc[4];
#pragma unroll
  for (int j = 0; j < 4; ++j) {
    const int u = t + 256 * j;
    ur[j] = u >> 4;
    uc[j] = (u & 15) * 8;
    xsrc[j] = x + (size_t)(b * Nn + n0 + ur[j]) * Cn + uc[j];
    hsrc[j] = Vhi + ur[j] * Cn + uc[j];
  }

  f32x4 acc[4];
#pragma unroll
  for (int i = 0; i < 4; ++i) acc[i] = (f32x4){0.f, 0.f, 0.f, 0.f};

  float4 px0[4], px1[4];
  short8 pvh[4], pvl[4];
#pragma unroll
  for (int j = 0; j < 4; ++j) {  // prologue prefetch: chunk 0
    px0[j] = *(const float4*)(xsrc[j]);
    px1[j] = *(const float4*)(xsrc[j] + 4);
    pvh[j] = *(const short8*)(hsrc[j]);
    pvl[j] = *(const short8*)(hsrc[j] + dlo);
  }

  for (int k0 = 0; k0 < Cn; k0 += 128) {
#pragma unroll
    for (int j = 0; j < 4; ++j) {
      short8 s;
      s[0] = bfbits(px0[j].x); s[1] = bfbits(px0[j].y);
      s[2] = bfbits(px0[j].z); s[3] = bfbits(px0[j].w);
      s[4] = bfbits(px1[j].x); s[5] = bfbits(px1[j].y);
      s[6] = bfbits(px1[j].z); s[7] = bfbits(px1[j].w);
      *(short8*)&Xs[ur[j]][uc[j]] = s;
      *(short8*)&VsH[ur[j]][uc[j]] = pvh[j];
      *(short8*)&VsL[ur[j]][uc[j]] = pvl[j];
    }
    __syncthreads();
    if (k0 + 128 < Cn) {  // prefetch next chunk while computing this one
#pragma unroll
      for (int j = 0; j < 4; ++j) {
        px0[j] = *(const float4*)(xsrc[j] + k0 + 128);
        px1[j] = *(const float4*)(xsrc[j] + k0 + 132);
        pvh[j] = *(const short8*)(hsrc[j] + k0 + 128);
        pvl[j] = *(const short8*)(hsrc[j] + dlo + k0 + 128);
      }
    }
#pragma unroll
    for (int kk = 0; kk < 128; kk += 32) {
      const short8 a = *(const short8*)&Xs[w * 16 + lr][kk + q * 8];
#pragma unroll
      for (int mt = 0; mt < 4; ++mt) {
        acc[mt] = MFMA16(a, *(const short8*)&VsH[mt * 16 + lr][kk + q * 8], acc[mt]);
        acc[mt] = MFMA16(a, *(const short8*)&VsL[mt * 16 + lr][kk + q * 8], acc[mt]);
      }
    }
    __syncthreads();
  }
  // D layout: row(n)=q*4+reg, col(m)=lr  [m89-verified]
#pragma unroll
  for (int mt = 0; mt < 4; ++mt) {
    const int m = mt * 16 + lr;
    const float bb = c0[m];
    float4 o;
    o.x = acc[mt][0] + bb; o.y = acc[mt][1] + bb;
    o.z = acc[mt][2] + bb; o.w = acc[mt][3] + bb;
    *(float4*)&logits[(size_t)(b * Mn + m) * Nn + n0 + w * 16 + q * 4] = o;
  }
}

// ---------------------------------------------------------------------------
// K2: softmax over N per (b,m) row; bf16 weights out. grid Bn*Mn, block 256
// ---------------------------------------------------------------------------
__global__ __launch_bounds__(256) void softmax_kernel(
    const float* __restrict__ logits, bf16* __restrict__ wgt) {
  const int row = blockIdx.x;
  const int t = threadIdx.x;
  const float* L = logits + (size_t)row * Nn;
  float v[16];
  float mx = -3.4e38f;
#pragma unroll
  for (int i = 0; i < 16; ++i) {
    v[i] = L[t + 256 * i];
    mx = fmaxf(mx, v[i]);
  }
#pragma unroll
  for (int off = 32; off > 0; off >>= 1) mx = fmaxf(mx, __shfl_down(mx, off));
  __shared__ float sred[4];
  if ((t & 63) == 0) sred[t >> 6] = mx;
  __syncthreads();
  mx = fmaxf(fmaxf(sred[0], sred[1]), fmaxf(sred[2], sred[3]));
  float sum = 0.f;
#pragma unroll
  for (int i = 0; i < 16; ++i) {
    v[i] = __expf(v[i] - mx);
    sum += v[i];
  }
#pragma unroll
  for (int off = 32; off > 0; off >>= 1) sum += __shfl_down(sum, off);
  __syncthreads();
  if ((t & 63) == 0) sred[t >> 6] = sum;
  __syncthreads();
  const float inv = 1.f / (sred[0] + sred[1] + sred[2] + sred[3]);
#pragma unroll
  for (int i = 0; i < 16; ++i)
    wgt[(size_t)row * Nn + t + 256 * i] = __float2bfloat16(v[i] * inv);
}

// ---------------------------------------------------------------------------
// K3: part[ks][b][m][c] = sum_{k-quarter} wgt[b][m][k]*x[b][k][c]
// K-chunks of 128.  Coalesced staging: thread (h=t&15,g=t>>4) loads rows
// {4g+i, 64+4g+i} cols [4h,4h+4) -> 16 lanes give 256B contiguous segments.
// 4x4 register transpose -> b64 writes into XT[c][k^swz], swz=8*((c>>2)&7)
// (write pos == read pos since swz only touches bits>=3; b128 reads
// conflict-free).  x prefetched 1 chunk ahead.  wgt A-frags direct from
// global (k-contiguous, L2-resident).  grid (Cn/64, Bn, 4) = 512, block 256.
// ---------------------------------------------------------------------------
__global__ __launch_bounds__(256) void pool_kernel(
    const float* __restrict__ x, const bf16* __restrict__ wgt,
    float* __restrict__ part) {
  const int cbase = blockIdx.x * 64;
  const int b = blockIdx.y;
  const int ks = blockIdx.z;
  const int t = threadIdx.x;
  __shared__ short XT[64][136];  // [c][k-swizzled]
  const int w = t >> 6, lane = t & 63, lr = lane & 15, q = lane >> 4;
  const int mh = (w & 1) * 32, ch = (w >> 1) * 32;
  f32x4 acc[2][2];
#pragma unroll
  for (int i = 0; i < 2; ++i)
#pragma unroll
    for (int j = 0; j < 2; ++j) acc[i][j] = (f32x4){0.f, 0.f, 0.f, 0.f};

  const int h = t & 15, g = t >> 4;
  const int swz = 8 * (h & 7);  // this thread's cols are 4h..4h+3 -> c>>2 == h
  const int swzr0 = 8 * (((ch + lr) >> 2) & 7);
  const int swzr1 = 8 * (((ch + 16 + lr) >> 2) & 7);
  const int kbase = ks * (Nn / 4);
  const float* xsrc = x + (size_t)b * Nn * Cn + (size_t)(kbase + 4 * g) * Cn + cbase + 4 * h;
  const bf16* wr0 = wgt + (size_t)(b * Mn + mh + lr) * Nn + kbase;
  const bf16* wr1 = wr0 + (size_t)16 * Nn;

  float4 pf[8];
#pragma unroll
  for (int i = 0; i < 4; ++i) {  // prologue prefetch: chunk 0
    pf[i]     = *(const float4*)(xsrc + (size_t)i * Cn);
    pf[4 + i] = *(const float4*)(xsrc + (size_t)(64 + i) * Cn);
  }

  for (int kc = 0; kc < Nn / 4; kc += 128) {
#pragma unroll
    for (int blk = 0; blk < 2; ++blk) {
      const float4 r0 = pf[blk * 4 + 0], r1 = pf[blk * 4 + 1];
      const float4 r2 = pf[blk * 4 + 2], r3 = pf[blk * 4 + 3];
      const int kof = (blk * 64 + 4 * g) ^ swz;
      short4x v0, v1, v2, v3;
      v0[0] = bfbits(r0.x); v0[1] = bfbits(r1.x); v0[2] = bfbits(r2.x); v0[3] = bfbits(r3.x);
      v1[0] = bfbits(r0.y); v1[1] = bfbits(r1.y); v1[2] = bfbits(r2.y); v1[3] = bfbits(r3.y);
      v2[0] = bfbits(r0.z); v2[1] = bfbits(r1.z); v2[2] = bfbits(r2.z); v2[3] = bfbits(r3.z);
      v3[0] = bfbits(r0.w); v3[1] = bfbits(r1.w); v3[2] = bfbits(r2.w); v3[3] = bfbits(r3.w);
      *(short4x*)&XT[4 * h + 0][kof] = v0;
      *(short4x*)&XT[4 * h + 1][kof] = v1;
      *(short4x*)&XT[4 * h + 2][kof] = v2;
      *(short4x*)&XT[4 * h + 3][kof] = v3;
    }
    __syncthreads();
    if (kc + 128 < Nn / 4) {  // prefetch next chunk
#pragma unroll
      for (int i = 0; i < 4; ++i) {
        pf[i]     = *(const float4*)(xsrc + (size_t)(kc + 128 + i) * Cn);
        pf[4 + i] = *(const float4*)(xsrc + (size_t)(kc + 192 + i) * Cn);
      }
    }
#pragma unroll
    for (int kk = 0; kk < 128; kk += 32) {
      const short8 a0 = *(const short8*)(wr0 + kc + kk + q * 8);
      const short8 a1 = *(const short8*)(wr1 + kc + kk + q * 8);
      const short8 b0 = *(const short8*)&XT[ch + lr][(kk + q * 8) ^ swzr0];
      const short8 b1 = *(const short8*)&XT[ch + 16 + lr][(kk + q * 8) ^ swzr1];
      acc[0][0] = MFMA16(a0, b0, acc[0][0]);
      acc[0][1] = MFMA16(a0, b1, acc[0][1]);
      acc[1][0] = MFMA16(a1, b0, acc[1][0]);
      acc[1][1] = MFMA16(a1, b1, acc[1][1]);
    }
    __syncthreads();
  }
  float* pout = part + ((size_t)ks * Bn + b) * Mn * Cn;
#pragma unroll
  for (int mi = 0; mi < 2; ++mi)
#pragma unroll
    for (int ci = 0; ci < 2; ++ci) {
      const int m = mh + mi * 16 + q * 4;
      const int c = cbase + ch + ci * 16 + lr;
#pragma unroll
      for (int reg = 0; reg < 4; ++reg)
        pout[(size_t)(m + reg) * Cn + c] = acc[mi][ci][reg];
    }
}

// ---------------------------------------------------------------------------
// K4: out = sum of 4 partials (float4).  grid 512, block 256
// ---------------------------------------------------------------------------
__global__ __launch_bounds__(256) void reduce_kernel(
    const float* __restrict__ part, float* __restrict__ out) {
  const int i = blockIdx.x * 256 + threadIdx.x;
  const float4* p = (const float4*)part;
  const int S4 = (Bn * Mn * Cn) / 4;
  const float4 v0 = p[i], v1 = p[i + S4], v2 = p[i + 2 * S4], v3 = p[i + 3 * S4];
  float4 o;
  o.x = (v0.x + v1.x) + (v2.x + v3.x);
  o.y = (v0.y + v1.y) + (v2.y + v3.y);
  o.z = (v0.z + v1.z) + (v2.z + v3.z);
  o.w = (v0.w + v1.w) + (v2.w + v3.w);
  ((float4*)out)[i] = o;
}

extern "C" void kernel_launch(void* const* d_in, const int* in_sizes, int n_in,
                              void* d_out, int out_size, void* d_ws, size_t ws_size,
                              hipStream_t stream) {
  const float* x = (const float*)d_in[0];
  const float* W = (const float*)d_in[1];
  const float* bias = (const float*)d_in[2];
  const float* av = (const float*)d_in[3];
  float* out = (float*)d_out;
  char* ws = (char*)d_ws;

  bf16* Vhi = (bf16*)(ws + 0);            // 131072 B
  bf16* Vlo = (bf16*)(ws + 131072);       // 131072 B
  float* c0 = (float*)(ws + 262144);      // 1024 B
  float* logits = (float*)(ws + 263168);  // 8388608 B
  bf16* wgt = (bf16*)(ws + 8651776);      // 4194304 B
  float* part = (float*)(ws + 12846080);  // 4 x 2097152 B  (total ~20.3 MB)

  prep_kernel<<<dim3(Mn, Cn / 64), 256, 0, stream>>>(W, bias, av, Vhi, Vlo, c0);
  logits_kernel<<<dim3(Nn / 64, Bn), 256, 0, stream>>>(x, Vhi, Vlo, c0, logits);
  softmax_kernel<<<Bn * Mn, 256, 0, stream>>>(logits, wgt);
  pool_kernel<<<dim3(Cn / 64, Bn, 4), 256, 0, stream>>>(x, wgt, part);
  reduce_kernel<<<(Bn * Mn * Cn) / 1024, 256, 0, stream>>>(part, out);
}